// Round 8
// baseline (15563.055 us; speedup 1.0000x reference)
//
#include <hip/hip_runtime.h>
#include <math.h>

// B=32, L=1024, D=256, G=768
#define NROWS 32768  // B*L

typedef float v4 __attribute__((ext_vector_type(4)));
typedef _Float16 h2 __attribute__((ext_vector_type(2)));
typedef _Float16 f16x8 __attribute__((ext_vector_type(8)));
typedef float f32x4 __attribute__((ext_vector_type(4)));

__device__ __forceinline__ float geluf(float x){ return 0.5f*x*(1.0f+erff(x*0.70710678118654752f)); }
__device__ __forceinline__ float sigm(float x){ return 1.0f/(1.0f+expf(-x)); }

// barrier that does NOT drain vmcnt: LDS visibility only. Global prefetch
// loads / output stores stay in flight across it.
__device__ __forceinline__ void wg_barrier(){
    asm volatile("s_waitcnt lgkmcnt(0)" ::: "memory");
    __builtin_amdgcn_s_barrier();
    __builtin_amdgcn_sched_barrier(0);
}

// ---------------- start embed: sh[b,d] ----------------
__global__ __launch_bounds__(256) void k_start_embed(
    const float* __restrict__ ne, const float* __restrict__ w0, const float* __restrict__ b0,
    const float* __restrict__ w1, const float* __restrict__ b1,
    const float* __restrict__ w2, const float* __restrict__ b2,
    float* __restrict__ sh)
{
    __shared__ __align__(16) float encL[1024];
    __shared__ __align__(16) float g1[256];
    __shared__ __align__(16) float g2[256];
    int b = blockIdx.x, t = threadIdx.x;
    for (int i = t; i < 1024; i += 256) encL[i] = ne[b*1024 + i];
    __syncthreads();
    const float4* wr = (const float4*)(w0 + (size_t)t*1024);
    const float4* e4 = (const float4*)encL;
    float a0=0,a1=0,a2=0,a3=0;
    #pragma unroll 8
    for (int k = 0; k < 256; ++k){ float4 w = wr[k], e = e4[k];
        a0 += w.x*e.x; a1 += w.y*e.y; a2 += w.z*e.z; a3 += w.w*e.w; }
    float t1 = a0+a1+a2+a3 + b0[t];
    float res = t1;
    g1[t] = geluf(t1);
    __syncthreads();
    const float4* w1r = (const float4*)(w1 + (size_t)t*256);
    const float4* g14 = (const float4*)g1;
    a0=a1=a2=a3=0.f;
    #pragma unroll 8
    for (int k = 0; k < 64; ++k){ float4 w = w1r[k], e = g14[k];
        a0 += w.x*e.x; a1 += w.y*e.y; a2 += w.z*e.z; a3 += w.w*e.w; }
    g2[t] = geluf(a0+a1+a2+a3 + b1[t]);
    __syncthreads();
    const float4* w2r = (const float4*)(w2 + (size_t)t*256);
    const float4* g24 = (const float4*)g2;
    a0=a1=a2=a3=0.f;
    #pragma unroll 8
    for (int k = 0; k < 64; ++k){ float4 w = w2r[k], e = g24[k];
        a0 += w.x*e.x; a1 += w.y*e.y; a2 += w.z*e.z; a3 += w.w*e.w; }
    sh[b*256 + t] = a0+a1+a2+a3 + b2[t] + res;
}

__device__ __forceinline__ f16x8 to_f16x8(float4 a, float4 b){
    f16x8 r;
    r[0]=(_Float16)a.x; r[1]=(_Float16)a.y; r[2]=(_Float16)a.z; r[3]=(_Float16)a.w;
    r[4]=(_Float16)b.x; r[5]=(_Float16)b.y; r[6]=(_Float16)b.z; r[7]=(_Float16)b.w;
    return r;
}

// ---------------- GRU scan v8: MFMA multi-batch ----------------
// grid = 2 WGs; WG handles batches [wg*16, wg*16+16). 1024 threads, 16 waves.
// Per step: hp[768,16] = W_hh[768,256] @ h[256,16] via v_mfma_f32_16x16x32_f16.
// Wave w owns dims [16w,16w+16) for ALL 3 gates (M-tiles w, 16+w, 32+w):
// gate combine is wave-local in the C-fragment layout (row=(l>>4)*4+reg,
// col = batch = l&15); fp32 master h in 4 regs/lane. A-fragments (weights,
// f16) loaded once: 24 frags x 4 regs = 96 (MFMA reads AGPRs natively ->
// low arch-VGPR demand ~80). h exchanged via double-buffered f16 hT with one
// lgkm-only barrier per step.
// A-frag: lane l holds A[m = Mbase + (l&15)][k = kt*32 + (l>>4)*8 + j]
// B-frag: lane l holds B[k = kt*32 + (l>>4)*8 + j][n = l&15]  (n = batch)
#define HPAD 264
template<int LAYER>
__global__ __launch_bounds__(1024, 4) void k_gru_mfma(
    const float* __restrict__ w_hh, const float* __restrict__ b_hh,
    const float* __restrict__ w_ih0, const float* __restrict__ b_ih0,
    const float* __restrict__ xp1,
    const int*   __restrict__ trg,
    const float* __restrict__ sh,
    float* __restrict__ out)
{
    __shared__ __align__(16) _Float16 hT[2][16][HPAD];
    __shared__ unsigned char bitL[16][1024];
    int wg = blockIdx.x, t = threadIdx.x;
    int w   = t >> 6;          // wave 0..15
    int l   = t & 63;          // lane
    int col = l & 15;          // batch-in-WG (C col / B n / A m)
    int g4  = l >> 4;          // lane group
    int d0  = w*16 + g4*4;     // this lane's first output dim (C rows d0..d0+3)
    int bg  = wg*16 + col;     // global batch for per-lane batch-indexed data

    if (LAYER == 0) {
        for (int i = t; i < 16*1024; i += 1024) {
            int b = i >> 10, s = i & 1023;
            bitL[b][s] = (s == 0) ? (unsigned char)1
                                  : (unsigned char)trg[(wg*16 + b)*1024 + s - 1];
        }
    }

    // ---- A fragments (weights), loaded once ----
    f16x8 afr[8], afz[8], afn[8];
    #pragma unroll
    for (int kt = 0; kt < 8; ++kt) {
        int kb = kt*32 + g4*8;
        const float4* pr = (const float4*)(w_hh + (size_t)(      w*16 + col)*256 + kb);
        const float4* pz = (const float4*)(w_hh + (size_t)(256 + w*16 + col)*256 + kb);
        const float4* pn = (const float4*)(w_hh + (size_t)(512 + w*16 + col)*256 + kb);
        afr[kt] = to_f16x8(pr[0], pr[1]);
        afz[kt] = to_f16x8(pz[0], pz[1]);
        afn[kt] = to_f16x8(pn[0], pn[1]);
    }
    // ---- per-lane row constants (C-layout rows d0..d0+3) ----
    float4 bhr = *(const float4*)(b_hh + d0);
    float4 bhz = *(const float4*)(b_hh + 256 + d0);
    float4 bhn = *(const float4*)(b_hh + 512 + d0);
    float4 wir, wiz, win, bir, biz, bin;
    if (LAYER == 0) {
        wir = *(const float4*)(w_ih0 + d0); wiz = *(const float4*)(w_ih0 + 256 + d0);
        win = *(const float4*)(w_ih0 + 512 + d0);
        bir = *(const float4*)(b_ih0 + d0); biz = *(const float4*)(b_ih0 + 256 + d0);
        bin = *(const float4*)(b_ih0 + 512 + d0);
    }

    // ---- h0 ----
    float4 h0 = *(const float4*)(sh + (size_t)bg*256 + d0);
    float hro[4] = {h0.x, h0.y, h0.z, h0.w};
    {   // seed hT[0][batch][dim] (each lane owns (col, d0..d0+3) once: w,g4 cover all dims)
        h2 pa; pa[0] = (_Float16)hro[0]; pa[1] = (_Float16)hro[1];
        h2 pb; pb[0] = (_Float16)hro[2]; pb[1] = (_Float16)hro[3];
        *(float2*)(&hT[0][col][d0]) = make_float2(__builtin_bit_cast(float, pa),
                                                  __builtin_bit_cast(float, pb));
    }
    // ---- xp prefetch for step 0 (layer 1) ----
    float4 xr, xz, xn;
    if (LAYER == 1) {
        const float* base = xp1 + (size_t)bg*768;
        xr = *(const float4*)(base + d0);
        xz = *(const float4*)(base + 256 + d0);
        xn = *(const float4*)(base + 512 + d0);
    }
    __syncthreads();

    for (int step = 0; step < 1024; ++step) {
        int cur = step & 1, nxt = cur ^ 1;
        // prefetch next step's xp (in flight across the lgkm-only barrier)
        float4 nxr, nxz, nxn;
        if (LAYER == 1) {
            int sn = (step < 1023) ? step + 1 : 1023;
            const float* base = xp1 + ((size_t)sn*32 + bg)*768;
            nxr = *(const float4*)(base + d0);
            nxz = *(const float4*)(base + 256 + d0);
            nxn = *(const float4*)(base + 512 + d0);
        }
        // ---- MFMA: hp = W . h over K=256 (8 K-tiles) ----
        f32x4 cr = {0.f,0.f,0.f,0.f}, cz = {0.f,0.f,0.f,0.f}, cn = {0.f,0.f,0.f,0.f};
        #pragma unroll
        for (int kt = 0; kt < 8; ++kt) {
            f16x8 bf = *(const f16x8*)(&hT[cur][col][kt*32 + g4*8]);
            cr = __builtin_amdgcn_mfma_f32_16x16x32_f16(afr[kt], bf, cr, 0, 0, 0);
            cz = __builtin_amdgcn_mfma_f32_16x16x32_f16(afz[kt], bf, cz, 0, 0, 0);
            cn = __builtin_amdgcn_mfma_f32_16x16x32_f16(afn[kt], bf, cn, 0, 0, 0);
        }
        // ---- gates (wave-local; lane handles rows d0..d0+3 for batch col) ----
        if (LAYER == 0) {
            float bit = (float)bitL[col][step];
            xr = make_float4(bir.x + bit*wir.x, bir.y + bit*wir.y, bir.z + bit*wir.z, bir.w + bit*wir.w);
            xz = make_float4(biz.x + bit*wiz.x, biz.y + bit*wiz.y, biz.z + bit*wiz.z, biz.w + bit*wiz.w);
            xn = make_float4(bin.x + bit*win.x, bin.y + bit*win.y, bin.z + bit*win.z, bin.w + bit*win.w);
        }
        float xrv[4] = {xr.x, xr.y, xr.z, xr.w};
        float xzv[4] = {xz.x, xz.y, xz.z, xz.w};
        float xnv[4] = {xn.x, xn.y, xn.z, xn.w};
        float bhrv[4] = {bhr.x, bhr.y, bhr.z, bhr.w};
        float bhzv[4] = {bhz.x, bhz.y, bhz.z, bhz.w};
        float bhnv[4] = {bhn.x, bhn.y, bhn.z, bhn.w};
        #pragma unroll
        for (int r = 0; r < 4; ++r) {
            float rr = sigm(xrv[r] + cr[r] + bhrv[r]);
            float zz = sigm(xzv[r] + cz[r] + bhzv[r]);
            float nn = tanhf(xnv[r] + rr*(cn[r] + bhnv[r]));
            hro[r] = (1.0f - zz)*nn + zz*hro[r];
        }
        // ---- write h' to LDS (f16, next buffer) + output (f32, global) ----
        {
            h2 pa; pa[0] = (_Float16)hro[0]; pa[1] = (_Float16)hro[1];
            h2 pb; pb[0] = (_Float16)hro[2]; pb[1] = (_Float16)hro[3];
            *(float2*)(&hT[nxt][col][d0]) = make_float2(__builtin_bit_cast(float, pa),
                                                        __builtin_bit_cast(float, pb));
        }
        {
            size_t oidx = (LAYER == 0) ? (((size_t)step*32 + bg)*256 + d0)
                                       : (((size_t)bg*1024 + step)*256 + d0);
            *(float4*)(out + oidx) = make_float4(hro[0], hro[1], hro[2], hro[3]);
        }
        wg_barrier();
        if (LAYER == 1) { xr = nxr; xz = nxz; xn = nxn; }
    }
}

// ---------------- generic fp32 GEMM: C[M,N] = act(A[M,K] @ B[N,K]^T + bias) ----------------
// aMode 0: plain A. aMode 3 (comb): K=768, k<256 -> A(ctx), k<512 -> A1(outs), else A2(sh, row=m>>10)
__global__ __launch_bounds__(256) void k_gemm(
    const float* __restrict__ A, const float* __restrict__ B,
    const float* __restrict__ bias, float* __restrict__ C,
    int M, int N, int K, int act, int aMode,
    const float* __restrict__ A1, const float* __restrict__ A2)
{
    __shared__ __align__(16) float As[16][128];
    __shared__ __align__(16) float Bs[16][128];
    int nbn = N >> 7;
    int bx = blockIdx.x % nbn, by = blockIdx.x / nbn;
    int m0 = by << 7, n0 = bx << 7;
    int t = threadIdx.x;
    int tm = t >> 4, tn = t & 15;
    float acc[8][8] = {};
    for (int kt = 0; kt < K; kt += 16) {
        __syncthreads();
        #pragma unroll
        for (int idx = t; idx < 512; idx += 256) {
            int m = idx >> 2, kc = idx & 3;
            int gk = kt + (kc << 2);
            float4 va;
            if (aMode == 0) {
                va = *(const float4*)(A + (size_t)(m0+m)*K + gk);
            } else {
                int part = gk >> 8, kk = gk & 255;
                const float* P = (part == 0) ? A : ((part == 1) ? A1 : A2);
                int row = (part == 2) ? ((m0+m) >> 10) : (m0+m);
                va = *(const float4*)(P + (size_t)row*256 + kk);
            }
            int kb = kc << 2;
            As[kb+0][m]=va.x; As[kb+1][m]=va.y; As[kb+2][m]=va.z; As[kb+3][m]=va.w;
            float4 vb = *(const float4*)(B + (size_t)(n0+m)*K + gk);
            Bs[kb+0][m]=vb.x; Bs[kb+1][m]=vb.y; Bs[kb+2][m]=vb.z; Bs[kb+3][m]=vb.w;
        }
        __syncthreads();
        #pragma unroll
        for (int k = 0; k < 16; ++k) {
            float4 a0 = *(const float4*)&As[k][tm*8];
            float4 a1 = *(const float4*)&As[k][tm*8+4];
            float4 q0 = *(const float4*)&Bs[k][tn*8];
            float4 q1 = *(const float4*)&Bs[k][tn*8+4];
            float av[8] = {a0.x,a0.y,a0.z,a0.w,a1.x,a1.y,a1.z,a1.w};
            float bv[8] = {q0.x,q0.y,q0.z,q0.w,q1.x,q1.y,q1.z,q1.w};
            #pragma unroll
            for (int i = 0; i < 8; ++i)
                #pragma unroll
                for (int j = 0; j < 8; ++j)
                    acc[i][j] += av[i]*bv[j];
        }
    }
    float bv[8];
    #pragma unroll
    for (int j = 0; j < 8; ++j) bv[j] = bias[n0 + tn*8 + j];
    #pragma unroll
    for (int i = 0; i < 8; ++i) {
        size_t row = (size_t)(m0 + tm*8 + i);
        float o[8];
        #pragma unroll
        for (int j = 0; j < 8; ++j) {
            float v = acc[i][j] + bv[j];
            if (act == 1) v = geluf(v);
            else if (act == 2) v = tanhf(v);
            o[j] = v;
        }
        float4* cp = (float4*)(C + row*N + n0 + tn*8);
        cp[0] = make_float4(o[0],o[1],o[2],o[3]);
        cp[1] = make_float4(o[4],o[5],o[6],o[7]);
    }
}

// ---------------- causal attention (flash-style), WG = (b, 16 rows) ----------------
__global__ __launch_bounds__(256) void k_attn(
    const float* __restrict__ outs, const float* __restrict__ modif, float* __restrict__ ctx)
{
    __shared__ __align__(16) float Qs[16][256];
    __shared__ __align__(16) float KVs[32][256];
    __shared__ __align__(16) float sS[16][32];
    __shared__ float rowScaleL[16];
    __shared__ float rowLL[16];
    int b = blockIdx.y, l0 = blockIdx.x << 4, t = threadIdx.x;
    for (int idx = t; idx < 1024; idx += 256) {
        int r = idx >> 6, k4 = idx & 63;
        *(float4*)&Qs[r][k4*4] = *(const float4*)(outs + ((size_t)b*1024 + l0 + r)*256 + k4*4);
    }
    int sr = t >> 4, sj = t & 15;          // softmax grouping
    int rp = t >> 5, cg = t & 31;          // PV grouping: rows 2rp,2rp+1; cols cg*8
    float rowM = -1e30f, rowL = 0.f;
    float accA[8] = {}, accB[8] = {};
    int nt = ((l0 + 14) >> 5) + 1;
    for (int tt = 0; tt < nt; ++tt) {
        int m0 = tt << 5;
        __syncthreads();
        for (int idx = t; idx < 2048; idx += 256) {      // stage K = modif rows
            int mm = idx >> 6, k4 = idx & 63;
            *(float4*)&KVs[mm][k4*4] = *(const float4*)(modif + ((size_t)b*1024 + m0 + mm)*256 + k4*4);
        }
        __syncthreads();
        {   // QK: thread -> (row sr, cols 2*sj, 2*sj+1)
            int mp = sj << 1;
            const float4* q4 = (const float4*)Qs[sr];
            const float4* x4 = (const float4*)KVs[mp];
            const float4* y4 = (const float4*)KVs[mp+1];
            float s0 = 0.f, s1 = 0.f;
            #pragma unroll 8
            for (int kk = 0; kk < 64; ++kk) {
                int k = (kk + sj) & 63;
                float4 q = q4[k], x = x4[k], y = y4[k];
                s0 += q.x*x.x + q.y*x.y + q.z*x.z + q.w*x.w;
                s1 += q.x*y.x + q.y*y.y + q.z*y.z + q.w*y.w;
            }
            int l = l0 + sr;
            if (m0 + mp     >= l) s0 = -1e30f;
            if (m0 + mp + 1 >= l) s1 = -1e30f;
            sS[sr][mp] = s0; sS[sr][mp+1] = s1;
        }
        __syncthreads();
        {   // online softmax update
            float v0 = sS[sr][sj], v1 = sS[sr][sj+16];
            float mx = fmaxf(v0, v1);
            for (int off = 8; off; off >>= 1) mx = fmaxf(mx, __shfl_xor(mx, off));
            float newM = fmaxf(rowM, mx);
            float scale, p0, p1;
            if (newM < -1e29f) { scale = 1.f; p0 = 0.f; p1 = 0.f; }
            else { scale = expf(rowM - newM); p0 = expf(v0 - newM); p1 = expf(v1 - newM); }
            rowM = newM;
            float ts = p0 + p1;
            for (int off = 8; off; off >>= 1) ts += __shfl_xor(ts, off);
            rowL = rowL*scale + ts;
            sS[sr][sj] = p0; sS[sr][sj+16] = p1;
            if (sj == 0) { rowScaleL[sr] = scale; rowLL[sr] = rowL; }
        }
        __syncthreads();
        for (int idx = t; idx < 2048; idx += 256) {      // stage V = outs rows
            int mm = idx >> 6, k4 = idx & 63;
            *(float4*)&KVs[mm][k4*4] = *(const float4*)(outs + ((size_t)b*1024 + m0 + mm)*256 + k4*4);
        }
        __syncthreads();
        {   // PV accumulate
            float sc0 = rowScaleL[2*rp], sc1 = rowScaleL[2*rp+1];
            #pragma unroll
            for (int j = 0; j < 8; ++j) { accA[j] *= sc0; accB[j] *= sc1; }
            int c0 = cg << 3;
            #pragma unroll 4
            for (int mm = 0; mm < 32; ++mm) {
                float p0 = sS[2*rp][mm], p1 = sS[2*rp+1][mm];
                float4 vA = *(const float4*)&KVs[mm][c0];
                float4 vB = *(const float4*)&KVs[mm][c0+4];
                accA[0] += p0*vA.x; accA[1] += p0*vA.y; accA[2] += p0*vA.z; accA[3] += p0*vA.w;
                accA[4] += p0*vB.x; accA[5] += p0*vB.y; accA[6] += p0*vB.z; accA[7] += p0*vB.w;
                accB[0] += p1*vA.x; accB[1] += p1*vA.y; accB[2] += p1*vA.z; accB[3] += p1*vA.w;
                accB[4] += p1*vB.x; accB[5] += p1*vB.y; accB[6] += p1*vB.z; accB[7] += p1*vB.w;
            }
        }
    }
    __syncthreads();
    int c0 = cg << 3;
    {
        int l = l0 + 2*rp;
        float inv = (l == 0) ? 0.f : 1.f/rowLL[2*rp];
        float4* cp = (float4*)(ctx + ((size_t)b*1024 + l)*256 + c0);
        cp[0] = make_float4(accA[0]*inv, accA[1]*inv, accA[2]*inv, accA[3]*inv);
        cp[1] = make_float4(accA[4]*inv, accA[5]*inv, accA[6]*inv, accA[7]*inv);
    }
    {
        int l = l0 + 2*rp + 1;
        float inv = 1.f/rowLL[2*rp+1];
        float4* cp = (float4*)(ctx + ((size_t)b*1024 + l)*256 + c0);
        cp[0] = make_float4(accB[0]*inv, accB[1]*inv, accB[2]*inv, accB[3]*inv);
        cp[1] = make_float4(accB[4]*inv, accB[5]*inv, accB[6]*inv, accB[7]*inv);
    }
}

// ---------------- final: logits + outputs ----------------
__global__ __launch_bounds__(256) void k_final(
    const float* __restrict__ h2v, const float* __restrict__ w2, const float* __restrict__ b2,
    const float* __restrict__ mask, float* __restrict__ out)
{
    int i = blockIdx.x*256 + threadIdx.x;   // < 32768
    const float4* h4 = (const float4*)(h2v + (size_t)i*256);
    const float4* w4 = (const float4*)w2;
    float a0=0,a1=0,a2=0,a3=0;
    #pragma unroll 8
    for (int k = 0; k < 64; ++k) {
        float4 h = h4[k], w = w4[k];
        a0 += h.x*w.x; a1 += h.y*w.y; a2 += h.z*w.z; a3 += h.w*w.w;
    }
    float lg = a0+a1+a2+a3 + b2[0];
    float p = sigm(lg);
    out[2*i]     = 1.0f - p;
    out[2*i + 1] = p;
    out[65536  + i] = (lg > 0.f) ? 1.0f : ((lg < 0.f) ? -1.0f : 0.0f);
    out[98304  + i] = mask[i];
    out[131072 + i] = lg;
}

extern "C" void kernel_launch(void* const* d_in, const int* in_sizes, int n_in,
                              void* d_out, int out_size, void* d_ws, size_t ws_size,
                              hipStream_t stream)
{
    const float* ne      = (const float*)d_in[0];
    const float* mask    = (const float*)d_in[1];
    const int*   trg     = (const int*)  d_in[2];
    const float* se_w0   = (const float*)d_in[3];
    const float* se_b0   = (const float*)d_in[4];
    const float* se_w1   = (const float*)d_in[5];
    const float* se_b1   = (const float*)d_in[6];
    const float* se_w2   = (const float*)d_in[7];
    const float* se_b2   = (const float*)d_in[8];
    const float* w_ih0   = (const float*)d_in[9];
    const float* w_hh0   = (const float*)d_in[10];
    const float* b_ih0   = (const float*)d_in[11];
    const float* b_hh0   = (const float*)d_in[12];
    const float* w_ih1   = (const float*)d_in[13];
    const float* w_hh1   = (const float*)d_in[14];
    const float* b_ih1   = (const float*)d_in[15];
    const float* b_hh1   = (const float*)d_in[16];
    const float* attn_w1 = (const float*)d_in[17];
    const float* attn_b1 = (const float*)d_in[18];
    const float* comb_w  = (const float*)d_in[19];
    const float* comb_b  = (const float*)d_in[20];
    const float* dec_w0  = (const float*)d_in[21];
    const float* dec_b0  = (const float*)d_in[22];
    const float* dec_w1  = (const float*)d_in[23];
    const float* dec_b1  = (const float*)d_in[24];
    const float* dec_w2  = (const float*)d_in[25];
    const float* dec_b2  = (const float*)d_in[26];

    float* W    = (float*)d_ws;
    float* sh   = W;                    // 8192
    float* o0   = W + 8192;             // [L,B,D] 8388608
    float* xp1  = W + 8396800;          // [L,B,G] 25165824
    float* outs = W + 33562624;         // [B,L,D] 8388608  (total 41951232 floats = 160 MB)
    float* modif = o0;                  // reuse (o0 dead after xp1 GEMM)
    float* ctx  = xp1;                  // reuse (xp1 dead after scan1)
    float* dec  = xp1 + 8388608;
    float* h1   = xp1 + 16777216;
    float* h2b  = o0;                   // reuse (modif dead after attention)
    float* out  = (float*)d_out;

    k_start_embed<<<32, 256, 0, stream>>>(ne, se_w0, se_b0, se_w1, se_b1, se_w2, se_b2, sh);
    k_gru_mfma<0><<<2, 1024, 0, stream>>>(w_hh0, b_hh0, w_ih0, b_ih0, nullptr, trg, sh, o0);
    k_gemm<<<1536, 256, 0, stream>>>(o0, w_ih1, b_ih1, xp1, NROWS, 768, 256, 0, 0, nullptr, nullptr);
    k_gru_mfma<1><<<2, 1024, 0, stream>>>(w_hh1, b_hh1, nullptr, nullptr, xp1, trg, sh, outs);
    k_gemm<<<512, 256, 0, stream>>>(outs, attn_w1, attn_b1, modif, NROWS, 256, 256, 0, 0, nullptr, nullptr);
    { dim3 ag(64, 32); k_attn<<<ag, 256, 0, stream>>>(outs, modif, ctx); }
    k_gemm<<<512, 256, 0, stream>>>(ctx, comb_w, comb_b, dec, NROWS, 256, 768, 2, 3, outs, sh);
    k_gemm<<<512, 256, 0, stream>>>(dec, dec_w0, dec_b0, h1, NROWS, 256, 256, 1, 0, nullptr, nullptr);
    k_gemm<<<512, 256, 0, stream>>>(h1, dec_w1, dec_b1, h2b, NROWS, 256, 256, 1, 0, nullptr, nullptr);
    k_final<<<128, 256, 0, stream>>>(h2b, dec_w2, dec_b2, mask, out);
}

// Round 9
// 4391.011 us; speedup vs baseline: 3.5443x; 3.5443x over previous
//
#include <hip/hip_runtime.h>
#include <math.h>

// B=32, L=1024, D=256, G=768
#define NROWS 32768  // B*L

typedef float v4 __attribute__((ext_vector_type(4)));
typedef _Float16 h2 __attribute__((ext_vector_type(2)));
typedef _Float16 f16x8 __attribute__((ext_vector_type(8)));
typedef float f32x4 __attribute__((ext_vector_type(4)));

__device__ __forceinline__ float geluf(float x){ return 0.5f*x*(1.0f+erff(x*0.70710678118654752f)); }
__device__ __forceinline__ float sigm(float x){ return 1.0f/(1.0f+expf(-x)); }

__device__ __forceinline__ float dot2(h2 a, h2 b, float c){
#if __has_builtin(__builtin_amdgcn_fdot2)
    return __builtin_amdgcn_fdot2(a, b, c, false);
#else
    return c + (float)a.x*(float)b.x + (float)a.y*(float)b.y;
#endif
}
__device__ __forceinline__ h2 cvt2(float2 a){ return h2{(_Float16)a.x, (_Float16)a.y}; }

// barrier that does NOT drain vmcnt: LDS visibility only. Global prefetch
// loads / output stores stay in flight across it.
__device__ __forceinline__ void wg_barrier(){
    asm volatile("s_waitcnt lgkmcnt(0)" ::: "memory");
    __builtin_amdgcn_s_barrier();
    __builtin_amdgcn_sched_barrier(0);
}

// ---------------- start embed: sh[b,d] ----------------
__global__ __launch_bounds__(256) void k_start_embed(
    const float* __restrict__ ne, const float* __restrict__ w0, const float* __restrict__ b0,
    const float* __restrict__ w1, const float* __restrict__ b1,
    const float* __restrict__ w2, const float* __restrict__ b2,
    float* __restrict__ sh)
{
    __shared__ __align__(16) float encL[1024];
    __shared__ __align__(16) float g1[256];
    __shared__ __align__(16) float g2[256];
    int b = blockIdx.x, t = threadIdx.x;
    for (int i = t; i < 1024; i += 256) encL[i] = ne[b*1024 + i];
    __syncthreads();
    const float4* wr = (const float4*)(w0 + (size_t)t*1024);
    const float4* e4 = (const float4*)encL;
    float a0=0,a1=0,a2=0,a3=0;
    #pragma unroll 8
    for (int k = 0; k < 256; ++k){ float4 w = wr[k], e = e4[k];
        a0 += w.x*e.x; a1 += w.y*e.y; a2 += w.z*e.z; a3 += w.w*e.w; }
    float t1 = a0+a1+a2+a3 + b0[t];
    float res = t1;
    g1[t] = geluf(t1);
    __syncthreads();
    const float4* w1r = (const float4*)(w1 + (size_t)t*256);
    const float4* g14 = (const float4*)g1;
    a0=a1=a2=a3=0.f;
    #pragma unroll 8
    for (int k = 0; k < 64; ++k){ float4 w = w1r[k], e = g14[k];
        a0 += w.x*e.x; a1 += w.y*e.y; a2 += w.z*e.z; a3 += w.w*e.w; }
    g2[t] = geluf(a0+a1+a2+a3 + b1[t]);
    __syncthreads();
    const float4* w2r = (const float4*)(w2 + (size_t)t*256);
    const float4* g24 = (const float4*)g2;
    a0=a1=a2=a3=0.f;
    #pragma unroll 8
    for (int k = 0; k < 64; ++k){ float4 w = w2r[k], e = g24[k];
        a0 += w.x*e.x; a1 += w.y*e.y; a2 += w.z*e.z; a3 += w.w*e.w; }
    sh[b*256 + t] = a0+a1+a2+a3 + b2[t] + res;
}

// ---------------- GRU scan v9: one gate-row per thread, full-K f16 in regs ----------------
// One WG per batch, 768 threads (12 waves). Thread t owns gate-row t (full K):
// 128 h2 = 128 weight VGPRs + ~25 state ~= 155. The 72KB LDS pad forces
// 1 WG/CU -> occupancy cap 3 waves/SIMD -> VGPR budget 170 >= 155 (the
// allocator's default 2-WG target of 85 regs is what spilled R2/R4/R6).
// h is read as full-wave same-address broadcasts (free). Gates recombined
// via hpL/xnL with two lgkm-only barriers per step.
template<int LAYER>
__global__ __launch_bounds__(768) void k_gru3(
    const float* __restrict__ w_hh, const float* __restrict__ b_hh,
    const float* __restrict__ w_ih0, const float* __restrict__ b_ih0,
    const float* __restrict__ xp1,
    const int*   __restrict__ trg,
    const float* __restrict__ sh,
    float* __restrict__ out)
{
    __shared__ __align__(16) _Float16 hbuf[2][256];
    __shared__ __align__(16) float hpL[768];
    __shared__ __align__(16) float xnL[256];
    __shared__ __align__(16) float bitL[1024];
    __shared__ float ldspad[18432];   // 72KB occupancy limiter (kept live below)
    int b = blockIdx.x, t = threadIdx.x;

    if (b_hh[0] == 12345.678f) ldspad[t] = 1.f;   // never true; prevents elision

    if (LAYER == 0)
        for (int i = t; i < 1024; i += 768)
            bitL[i] = (i == 0) ? 1.0f : (float)trg[b*1024 + i - 1];

    // full-K f16 weights for gate-row t
    h2 wf[128];
    {
        const float2* src = (const float2*)(w_hh + (size_t)t*256);
        #pragma unroll
        for (int k = 0; k < 128; ++k) wf[k] = cvt2(src[k]);
    }
    float bhh = b_hh[t];
    float wi = 0.f, bi = 0.f;
    if (LAYER == 0) { wi = w_ih0[t]; bi = b_ih0[t]; }

    float hreg = 0.f;
    if (t < 256) { hreg = sh[b*256 + t]; hbuf[0][t] = (_Float16)hreg; }

    float xp = 0.f;
    if (LAYER == 1) xp = xp1[(size_t)b*768 + t];      // step-0 row (0*32+b)
    __syncthreads();

    for (int l = 0; l < 1024; ++l) {
        float nxp = 0.f;
        if (LAYER == 1) {
            int ln = (l < 1023) ? (l + 1) : 1023;
            nxp = xp1[((size_t)ln*32 + b)*768 + t];   // in flight across barriers
        }
        if (LAYER == 0) xp = bi + bitL[l]*wi;
        const float4* hb4 = (const float4*)(&hbuf[l & 1][0]);
        float a0 = 0.f, a1 = 0.f;
        #pragma unroll
        for (int k = 0; k < 32; ++k) {
            float4 hv = hb4[k];                        // wave-broadcast (free)
            a0 = dot2(wf[4*k+0], __builtin_bit_cast(h2, hv.x), a0);
            a1 = dot2(wf[4*k+1], __builtin_bit_cast(h2, hv.y), a1);
            a0 = dot2(wf[4*k+2], __builtin_bit_cast(h2, hv.z), a0);
            a1 = dot2(wf[4*k+3], __builtin_bit_cast(h2, hv.w), a1);
        }
        float hp = a0 + a1 + bhh;
        if (t < 512) hpL[t] = hp + xp;
        else { hpL[t] = hp; xnL[t - 512] = xp; }
        wg_barrier();
        if (t < 256) {
            float r = sigm(hpL[t]);
            float z = sigm(hpL[256 + t]);
            float n = tanhf(xnL[t] + r*hpL[512 + t]);
            hreg = (1.0f - z)*n + z*hreg;
            hbuf[(l + 1) & 1][t] = (_Float16)hreg;
            size_t oidx = (LAYER == 0) ? (((size_t)l*32 + b)*256 + t)
                                       : (((size_t)b*1024 + l)*256 + t);
            out[oidx] = hreg;
        }
        wg_barrier();
        if (LAYER == 1) xp = nxp;
    }
}

// ---------------- f16 MFMA GEMM: C[M,N] = act(A[M,K] @ B[N,K]^T + bias) ----------------
// 128x128 tile, 256 threads (4 waves); wave w -> 64x64 quadrant (wm=w>>1, wn=w&1).
// fp32 global -> f16 LDS staging (rows padded to 40 f16: 16B-aligned b128 frag
// reads, <=2-way bank aliasing). Fragment conventions verified on-device (R8):
// A-frag lane l: A[m + (l&15)][kt + (l>>4)*8 + j]; C row=(l>>4)*4+reg, col=l&15.
// aMode 0: plain A. aMode 3 (comb): K=768, part 0 ctx / 1 outs / 2 sh(row=m>>10).
__global__ __launch_bounds__(256, 3) void k_gemm_mfma(
    const float* __restrict__ A, const float* __restrict__ B,
    const float* __restrict__ bias, float* __restrict__ C,
    int M, int N, int K, int act, int aMode,
    const float* __restrict__ A1, const float* __restrict__ A2)
{
    __shared__ __align__(16) _Float16 As[128][40];
    __shared__ __align__(16) _Float16 Bs[128][40];
    int nbn = N >> 7;
    int bx = blockIdx.x % nbn, by = blockIdx.x / nbn;
    int m0 = by << 7, n0 = bx << 7;
    int t = threadIdx.x;
    int w = t >> 6, l = t & 63;
    int wm = w >> 1, wn = w & 1;
    int lc = l & 15, lg = l >> 4;
    f32x4 acc[4][4] = {};
    for (int kt = 0; kt < K; kt += 32) {
        __syncthreads();
        #pragma unroll
        for (int p = 0; p < 4; ++p) {
            int slot = t + p*256;            // 1024 slots: (m, kc)
            int m = slot >> 3, kc = slot & 7;
            int gk = kt + kc*4;
            float4 va;
            if (aMode == 0) {
                va = *(const float4*)(A + (size_t)(m0+m)*K + gk);
            } else {
                int part = gk >> 8, kk = gk & 255;
                const float* P = (part == 0) ? A : ((part == 1) ? A1 : A2);
                int row = (part == 2) ? ((m0+m) >> 10) : (m0+m);
                va = *(const float4*)(P + (size_t)row*256 + kk);
            }
            h2 pa; pa[0] = (_Float16)va.x; pa[1] = (_Float16)va.y;
            h2 pb; pb[0] = (_Float16)va.z; pb[1] = (_Float16)va.w;
            *(float2*)(&As[m][kc*4]) = make_float2(__builtin_bit_cast(float, pa),
                                                   __builtin_bit_cast(float, pb));
            float4 vb = *(const float4*)(B + (size_t)(n0+m)*K + gk);
            h2 qa; qa[0] = (_Float16)vb.x; qa[1] = (_Float16)vb.y;
            h2 qb; qb[0] = (_Float16)vb.z; qb[1] = (_Float16)vb.w;
            *(float2*)(&Bs[m][kc*4]) = make_float2(__builtin_bit_cast(float, qa),
                                                   __builtin_bit_cast(float, qb));
        }
        __syncthreads();
        f16x8 af[4], bf[4];
        #pragma unroll
        for (int mt = 0; mt < 4; ++mt)
            af[mt] = *(const f16x8*)(&As[wm*64 + mt*16 + lc][lg*8]);
        #pragma unroll
        for (int nt = 0; nt < 4; ++nt)
            bf[nt] = *(const f16x8*)(&Bs[wn*64 + nt*16 + lc][lg*8]);
        #pragma unroll
        for (int mt = 0; mt < 4; ++mt)
            #pragma unroll
            for (int nt = 0; nt < 4; ++nt)
                acc[mt][nt] = __builtin_amdgcn_mfma_f32_16x16x32_f16(af[mt], bf[nt], acc[mt][nt], 0, 0, 0);
    }
    #pragma unroll
    for (int nt = 0; nt < 4; ++nt) {
        int col = n0 + wn*64 + nt*16 + lc;
        float bv = bias[col];
        #pragma unroll
        for (int mt = 0; mt < 4; ++mt) {
            int rbase = m0 + wm*64 + mt*16 + lg*4;
            #pragma unroll
            for (int r = 0; r < 4; ++r) {
                float v = acc[mt][nt][r] + bv;
                if (act == 1) v = geluf(v);
                else if (act == 2) v = tanhf(v);
                C[(size_t)(rbase + r)*N + col] = v;
            }
        }
    }
}

// ---------------- causal attention (flash-style), WG = (b, 16 rows) ----------------
__global__ __launch_bounds__(256) void k_attn(
    const float* __restrict__ outs, const float* __restrict__ modif, float* __restrict__ ctx)
{
    __shared__ __align__(16) float Qs[16][256];
    __shared__ __align__(16) float KVs[32][256];
    __shared__ __align__(16) float sS[16][32];
    __shared__ float rowScaleL[16];
    __shared__ float rowLL[16];
    int b = blockIdx.y, l0 = blockIdx.x << 4, t = threadIdx.x;
    for (int idx = t; idx < 1024; idx += 256) {
        int r = idx >> 6, k4 = idx & 63;
        *(float4*)&Qs[r][k4*4] = *(const float4*)(outs + ((size_t)b*1024 + l0 + r)*256 + k4*4);
    }
    int sr = t >> 4, sj = t & 15;
    int rp = t >> 5, cg = t & 31;
    float rowM = -1e30f, rowL = 0.f;
    float accA[8] = {}, accB[8] = {};
    int nt = ((l0 + 14) >> 5) + 1;
    for (int tt = 0; tt < nt; ++tt) {
        int m0 = tt << 5;
        __syncthreads();
        for (int idx = t; idx < 2048; idx += 256) {
            int mm = idx >> 6, k4 = idx & 63;
            *(float4*)&KVs[mm][k4*4] = *(const float4*)(modif + ((size_t)b*1024 + m0 + mm)*256 + k4*4);
        }
        __syncthreads();
        {
            int mp = sj << 1;
            const float4* q4 = (const float4*)Qs[sr];
            const float4* x4 = (const float4*)KVs[mp];
            const float4* y4 = (const float4*)KVs[mp+1];
            float s0 = 0.f, s1 = 0.f;
            #pragma unroll 8
            for (int kk = 0; kk < 64; ++kk) {
                int k = (kk + sj) & 63;
                float4 q = q4[k], x = x4[k], y = y4[k];
                s0 += q.x*x.x + q.y*x.y + q.z*x.z + q.w*x.w;
                s1 += q.x*y.x + q.y*y.y + q.z*y.z + q.w*y.w;
            }
            int l = l0 + sr;
            if (m0 + mp     >= l) s0 = -1e30f;
            if (m0 + mp + 1 >= l) s1 = -1e30f;
            sS[sr][mp] = s0; sS[sr][mp+1] = s1;
        }
        __syncthreads();
        {
            float v0 = sS[sr][sj], v1 = sS[sr][sj+16];
            float mx = fmaxf(v0, v1);
            for (int off = 8; off; off >>= 1) mx = fmaxf(mx, __shfl_xor(mx, off));
            float newM = fmaxf(rowM, mx);
            float scale, p0, p1;
            if (newM < -1e29f) { scale = 1.f; p0 = 0.f; p1 = 0.f; }
            else { scale = expf(rowM - newM); p0 = expf(v0 - newM); p1 = expf(v1 - newM); }
            rowM = newM;
            float ts = p0 + p1;
            for (int off = 8; off; off >>= 1) ts += __shfl_xor(ts, off);
            rowL = rowL*scale + ts;
            sS[sr][sj] = p0; sS[sr][sj+16] = p1;
            if (sj == 0) { rowScaleL[sr] = scale; rowLL[sr] = rowL; }
        }
        __syncthreads();
        for (int idx = t; idx < 2048; idx += 256) {
            int mm = idx >> 6, k4 = idx & 63;
            *(float4*)&KVs[mm][k4*4] = *(const float4*)(outs + ((size_t)b*1024 + m0 + mm)*256 + k4*4);
        }
        __syncthreads();
        {
            float sc0 = rowScaleL[2*rp], sc1 = rowScaleL[2*rp+1];
            #pragma unroll
            for (int j = 0; j < 8; ++j) { accA[j] *= sc0; accB[j] *= sc1; }
            int c0 = cg << 3;
            #pragma unroll 4
            for (int mm = 0; mm < 32; ++mm) {
                float p0 = sS[2*rp][mm], p1 = sS[2*rp+1][mm];
                float4 vA = *(const float4*)&KVs[mm][c0];
                float4 vB = *(const float4*)&KVs[mm][c0+4];
                accA[0] += p0*vA.x; accA[1] += p0*vA.y; accA[2] += p0*vA.z; accA[3] += p0*vA.w;
                accA[4] += p0*vB.x; accA[5] += p0*vB.y; accA[6] += p0*vB.z; accA[7] += p0*vB.w;
                accB[0] += p1*vA.x; accB[1] += p1*vA.y; accB[2] += p1*vA.z; accB[3] += p1*vA.w;
                accB[4] += p1*vB.x; accB[5] += p1*vB.y; accB[6] += p1*vB.z; accB[7] += p1*vB.w;
            }
        }
    }
    __syncthreads();
    int c0 = cg << 3;
    {
        int l = l0 + 2*rp;
        float inv = (l == 0) ? 0.f : 1.f/rowLL[2*rp];
        float4* cp = (float4*)(ctx + ((size_t)b*1024 + l)*256 + c0);
        cp[0] = make_float4(accA[0]*inv, accA[1]*inv, accA[2]*inv, accA[3]*inv);
        cp[1] = make_float4(accA[4]*inv, accA[5]*inv, accA[6]*inv, accA[7]*inv);
    }
    {
        int l = l0 + 2*rp + 1;
        float inv = 1.f/rowLL[2*rp+1];
        float4* cp = (float4*)(ctx + ((size_t)b*1024 + l)*256 + c0);
        cp[0] = make_float4(accB[0]*inv, accB[1]*inv, accB[2]*inv, accB[3]*inv);
        cp[1] = make_float4(accB[4]*inv, accB[5]*inv, accB[6]*inv, accB[7]*inv);
    }
}

// ---------------- final: logits + outputs ----------------
__global__ __launch_bounds__(256) void k_final(
    const float* __restrict__ h2v, const float* __restrict__ w2, const float* __restrict__ b2,
    const float* __restrict__ mask, float* __restrict__ out)
{
    int i = blockIdx.x*256 + threadIdx.x;   // < 32768
    const float4* h4 = (const float4*)(h2v + (size_t)i*256);
    const float4* w4 = (const float4*)w2;
    float a0=0,a1=0,a2=0,a3=0;
    #pragma unroll 8
    for (int k = 0; k < 64; ++k) {
        float4 h = h4[k], w = w4[k];
        a0 += h.x*w.x; a1 += h.y*w.y; a2 += h.z*w.z; a3 += h.w*w.w;
    }
    float lg = a0+a1+a2+a3 + b2[0];
    float p = sigm(lg);
    out[2*i]     = 1.0f - p;
    out[2*i + 1] = p;
    out[65536  + i] = (lg > 0.f) ? 1.0f : ((lg < 0.f) ? -1.0f : 0.0f);
    out[98304  + i] = mask[i];
    out[131072 + i] = lg;
}

extern "C" void kernel_launch(void* const* d_in, const int* in_sizes, int n_in,
                              void* d_out, int out_size, void* d_ws, size_t ws_size,
                              hipStream_t stream)
{
    const float* ne      = (const float*)d_in[0];
    const float* mask    = (const float*)d_in[1];
    const int*   trg     = (const int*)  d_in[2];
    const float* se_w0   = (const float*)d_in[3];
    const float* se_b0   = (const float*)d_in[4];
    const float* se_w1   = (const float*)d_in[5];
    const float* se_b1   = (const float*)d_in[6];
    const float* se_w2   = (const float*)d_in[7];
    const float* se_b2   = (const float*)d_in[8];
    const float* w_ih0   = (const float*)d_in[9];
    const float* w_hh0   = (const float*)d_in[10];
    const float* b_ih0   = (const float*)d_in[11];
    const float* b_hh0   = (const float*)d_in[12];
    const float* w_ih1   = (const float*)d_in[13];
    const float* w_hh1   = (const float*)d_in[14];
    const float* b_ih1   = (const float*)d_in[15];
    const float* b_hh1   = (const float*)d_in[16];
    const float* attn_w1 = (const float*)d_in[17];
    const float* attn_b1 = (const float*)d_in[18];
    const float* comb_w  = (const float*)d_in[19];
    const float* comb_b  = (const float*)d_in[20];
    const float* dec_w0  = (const float*)d_in[21];
    const float* dec_b0  = (const float*)d_in[22];
    const float* dec_w1  = (const float*)d_in[23];
    const float* dec_b1  = (const float*)d_in[24];
    const float* dec_w2  = (const float*)d_in[25];
    const float* dec_b2  = (const float*)d_in[26];

    float* W    = (float*)d_ws;
    float* sh   = W;                    // 8192
    float* o0   = W + 8192;             // [L,B,D] 8388608
    float* xp1  = W + 8396800;          // [L,B,G] 25165824
    float* outs = W + 33562624;         // [B,L,D] 8388608  (total 41951232 floats = 160 MB)
    float* modif = o0;                  // reuse (o0 dead after xp1 GEMM)
    float* ctx  = xp1;                  // reuse (xp1 dead after scan1)
    float* dec  = xp1 + 8388608;
    float* h1   = xp1 + 16777216;
    float* h2b  = o0;                   // reuse (modif dead after attention)
    float* out  = (float*)d_out;

    k_start_embed<<<32, 256, 0, stream>>>(ne, se_w0, se_b0, se_w1, se_b1, se_w2, se_b2, sh);
    k_gru3<0><<<32, 768, 0, stream>>>(w_hh0, b_hh0, w_ih0, b_ih0, nullptr, trg, sh, o0);
    k_gemm_mfma<<<1536, 256, 0, stream>>>(o0, w_ih1, b_ih1, xp1, NROWS, 768, 256, 0, 0, nullptr, nullptr);
    k_gru3<1><<<32, 768, 0, stream>>>(w_hh1, b_hh1, nullptr, nullptr, xp1, trg, sh, outs);
    k_gemm_mfma<<<512, 256, 0, stream>>>(outs, attn_w1, attn_b1, modif, NROWS, 256, 256, 0, 0, nullptr, nullptr);
    { dim3 ag(64, 32); k_attn<<<ag, 256, 0, stream>>>(outs, modif, ctx); }
    k_gemm_mfma<<<512, 256, 0, stream>>>(ctx, comb_w, comb_b, dec, NROWS, 256, 768, 2, 3, outs, sh);
    k_gemm_mfma<<<512, 256, 0, stream>>>(dec, dec_w0, dec_b0, h1, NROWS, 256, 256, 1, 0, nullptr, nullptr);
    k_gemm_mfma<<<512, 256, 0, stream>>>(h1, dec_w1, dec_b1, h2b, NROWS, 256, 256, 1, 0, nullptr, nullptr);
    k_final<<<128, 256, 0, stream>>>(h2b, dec_w2, dec_b2, mask, out);
}

// Round 10
// 3694.106 us; speedup vs baseline: 4.2129x; 1.1887x over previous
//
#include <hip/hip_runtime.h>
#include <math.h>

// B=32, L=1024, D=256, G=768
#define NROWS 32768  // B*L

typedef float v4 __attribute__((ext_vector_type(4)));
typedef _Float16 h2 __attribute__((ext_vector_type(2)));
typedef _Float16 f16x8 __attribute__((ext_vector_type(8)));
typedef float f32x4 __attribute__((ext_vector_type(4)));

__device__ __forceinline__ float geluf(float x){ return 0.5f*x*(1.0f+erff(x*0.70710678118654752f)); }
__device__ __forceinline__ float sigm(float x){ return 1.0f/(1.0f+expf(-x)); }

__device__ __forceinline__ float dot2(h2 a, h2 b, float c){
#if __has_builtin(__builtin_amdgcn_fdot2)
    return __builtin_amdgcn_fdot2(a, b, c, false);
#else
    return c + (float)a.x*(float)b.x + (float)a.y*(float)b.y;
#endif
}
__device__ __forceinline__ h2 cvt2(float2 a){ return h2{(_Float16)a.x, (_Float16)a.y}; }

// barrier that does NOT drain vmcnt: LDS visibility only. Global prefetch
// loads / output stores stay in flight across it.
__device__ __forceinline__ void wg_barrier(){
    asm volatile("s_waitcnt lgkmcnt(0)" ::: "memory");
    __builtin_amdgcn_s_barrier();
    __builtin_amdgcn_sched_barrier(0);
}

// ---------------- start embed: sh[b,d] ----------------
__global__ __launch_bounds__(256) void k_start_embed(
    const float* __restrict__ ne, const float* __restrict__ w0, const float* __restrict__ b0,
    const float* __restrict__ w1, const float* __restrict__ b1,
    const float* __restrict__ w2, const float* __restrict__ b2,
    float* __restrict__ sh)
{
    __shared__ __align__(16) float encL[1024];
    __shared__ __align__(16) float g1[256];
    __shared__ __align__(16) float g2[256];
    int b = blockIdx.x, t = threadIdx.x;
    for (int i = t; i < 1024; i += 256) encL[i] = ne[b*1024 + i];
    __syncthreads();
    const float4* wr = (const float4*)(w0 + (size_t)t*1024);
    const float4* e4 = (const float4*)encL;
    float a0=0,a1=0,a2=0,a3=0;
    #pragma unroll 8
    for (int k = 0; k < 256; ++k){ float4 w = wr[k], e = e4[k];
        a0 += w.x*e.x; a1 += w.y*e.y; a2 += w.z*e.z; a3 += w.w*e.w; }
    float t1 = a0+a1+a2+a3 + b0[t];
    float res = t1;
    g1[t] = geluf(t1);
    __syncthreads();
    const float4* w1r = (const float4*)(w1 + (size_t)t*256);
    const float4* g14 = (const float4*)g1;
    a0=a1=a2=a3=0.f;
    #pragma unroll 8
    for (int k = 0; k < 64; ++k){ float4 w = w1r[k], e = g14[k];
        a0 += w.x*e.x; a1 += w.y*e.y; a2 += w.z*e.z; a3 += w.w*e.w; }
    g2[t] = geluf(a0+a1+a2+a3 + b1[t]);
    __syncthreads();
    const float4* w2r = (const float4*)(w2 + (size_t)t*256);
    const float4* g24 = (const float4*)g2;
    a0=a1=a2=a3=0.f;
    #pragma unroll 8
    for (int k = 0; k < 64; ++k){ float4 w = w2r[k], e = g24[k];
        a0 += w.x*e.x; a1 += w.y*e.y; a2 += w.z*e.z; a3 += w.w*e.w; }
    sh[b*256 + t] = a0+a1+a2+a3 + b2[t] + res;
}

// permuted f16 index within an hbuf row for hidden dim:
// dim = (hi:2)(mid:3)(lo:3) -> idx = mid*32 + hi*8 + lo  (bijective).
// Float4 slot s = mid*4 + hi holds dims hi*64 + mid*8 .. +8. K-half reads
// become 2-address wave broadcasts (conflict-free); writes 2-way (free).
__device__ __forceinline__ int hperm(int dim){
    return ((dim >> 3) & 7)*32 + ((dim >> 6) << 3) + (dim & 7);
}

// ---------------- GRU scan v10: v6 structure + REAL 1-WG/CU LDS pad ----------------
// Grant model (confirmed R3-R9): VGPR grant = 512 per-SIMD regs /
// (waves_per_SIMD x WGs_that_fit_by_LDS). v6 failed because 2 WGs fit ->
// grant 128 < 192-reg weight set. The 80KB pad makes LDS ~86KB -> 2 WGs
// need 172KB > 160KB/CU -> 1 WG/CU -> 8 waves = 2/SIMD -> grant 256.
// Thread (d = t>>1, half = t&1) owns gate rows d (r), d+256 (z), d+512 (n)
// over K-half [half*128, +128): 3 x 64 h2 = 192 weight VGPRs + ~40 state
// < 256 -> NO spill. Pair partials combined with one __shfl_xor(.,1) per
// gate. h kept f16 in LDS (hperm layout), fp32 master h in a register;
// one lgkm-only barrier per step.
template<int LAYER>
__global__ __launch_bounds__(512) void k_gru3(
    const float* __restrict__ w_hh, const float* __restrict__ b_hh,
    const float* __restrict__ w_ih0, const float* __restrict__ b_ih0,
    const float* __restrict__ xp1,
    const int*   __restrict__ trg,
    const float* __restrict__ sh,
    float* __restrict__ out)
{
    __shared__ __align__(16) _Float16 hbuf[2][256];
    __shared__ __align__(16) float bitL[1024];
    __shared__ float ldspad[20480];   // 80KB occupancy limiter -> 1 WG/CU on 160KB LDS
    int b = blockIdx.x, t = threadIdx.x;
    int d = t >> 1, half = t & 1;

    if (b_hh[0] == 12345.678f) ldspad[t] = 1.f;   // never true; prevents elision

    if (LAYER == 0) {
        #pragma unroll
        for (int i = 0; i < 2; ++i) {
            int idx = t + i*512;
            bitL[idx] = (idx == 0) ? 1.0f : (float)trg[b*1024 + idx - 1];
        }
    }

    // --- this thread's K-half of 3 gate rows into registers (f16 packed) ---
    h2 wR[64], wZ[64], wN[64];
    {
        const float2* wr = (const float2*)(w_hh + (size_t)d*256       + half*128);
        const float2* wz = (const float2*)(w_hh + (size_t)(d+256)*256 + half*128);
        const float2* wn = (const float2*)(w_hh + (size_t)(d+512)*256 + half*128);
        #pragma unroll
        for (int k = 0; k < 64; ++k) {
            wR[k] = cvt2(wr[k]); wZ[k] = cvt2(wz[k]); wN[k] = cvt2(wn[k]);
        }
    }
    float bhr = b_hh[d], bhz = b_hh[256 + d], bhn = b_hh[512 + d];
    float wir=0.f, wiz=0.f, win=0.f, bir=0.f, biz=0.f, bin=0.f;
    if (LAYER == 0) {
        wir = w_ih0[d]; wiz = w_ih0[256 + d]; win = w_ih0[512 + d];
        bir = b_ih0[d]; biz = b_ih0[256 + d]; bin = b_ih0[512 + d];
    }

    float hreg = sh[b*256 + d];
    if (half == 0) hbuf[0][hperm(d)] = (_Float16)hreg;

    float xr, xz, xn;
    if (LAYER == 1) {
        size_t base = (size_t)b*768;
        xr = xp1[base + d]; xz = xp1[base + 256 + d]; xn = xp1[base + 512 + d];
    }
    __syncthreads();

    for (int l = 0; l < 1024; ++l) {
        // prefetch next step's xp (stays in flight across the lgkm-only barrier)
        float nxr, nxz, nxn;
        if (LAYER == 1) {
            int ln = (l < 1023) ? (l + 1) : 1023;
            size_t base = ((size_t)ln*32 + b)*768;
            nxr = xp1[base + d]; nxz = xp1[base + 256 + d]; nxn = xp1[base + 512 + d];
        }
        // --- partial dots over this thread's K-half ---
        const float4* hb4 = (const float4*)(&hbuf[l & 1][0]);
        float ar = 0.f, az = 0.f, an = 0.f;
        #pragma unroll
        for (int kk = 0; kk < 16; ++kk) {
            // permuted slot holding dims half*128 + kk*8 .. +8
            float4 hv = hb4[(kk & 7)*4 + half*2 + (kk >> 3)];
            h2 h0 = __builtin_bit_cast(h2, hv.x);
            h2 h1 = __builtin_bit_cast(h2, hv.y);
            h2 hc = __builtin_bit_cast(h2, hv.z);
            h2 h3 = __builtin_bit_cast(h2, hv.w);
            ar = dot2(wR[4*kk+0], h0, ar); ar = dot2(wR[4*kk+1], h1, ar);
            ar = dot2(wR[4*kk+2], hc, ar); ar = dot2(wR[4*kk+3], h3, ar);
            az = dot2(wZ[4*kk+0], h0, az); az = dot2(wZ[4*kk+1], h1, az);
            az = dot2(wZ[4*kk+2], hc, az); az = dot2(wZ[4*kk+3], h3, az);
            an = dot2(wN[4*kk+0], h0, an); an = dot2(wN[4*kk+1], h1, an);
            an = dot2(wN[4*kk+2], hc, an); an = dot2(wN[4*kk+3], h3, an);
        }
        // combine K-halves (partner = lane^1, same wave)
        ar += __shfl_xor(ar, 1);
        az += __shfl_xor(az, 1);
        an += __shfl_xor(an, 1);
        // --- gates (both lanes of the pair compute identically) ---
        if (LAYER == 0) {
            float bit = bitL[l];
            xr = bir + bit*wir; xz = biz + bit*wiz; xn = bin + bit*win;
        }
        float r = sigm(xr + ar + bhr);
        float z = sigm(xz + az + bhz);
        float n = tanhf(xn + r*(an + bhn));
        hreg = (1.0f - z)*n + z*hreg;
        if (half == 0) {
            hbuf[(l + 1) & 1][hperm(d)] = (_Float16)hreg;
        } else {
            size_t oidx = (LAYER == 0) ? (((size_t)l*32 + b)*256 + d)
                                       : (((size_t)b*1024 + l)*256 + d);
            out[oidx] = hreg;
        }
        wg_barrier();
        if (LAYER == 1) { xr = nxr; xz = nxz; xn = nxn; }
    }
}

// ---------------- f16 MFMA GEMM: C[M,N] = act(A[M,K] @ B[N,K]^T + bias) ----------------
// 128x128 tile, 256 threads (4 waves); wave w -> 64x64 quadrant (wm=w>>1, wn=w&1).
// fp32 global -> f16 LDS staging (rows padded to 40 f16: 16B-aligned b128 frag
// reads, <=2-way bank aliasing). Fragment conventions verified on-device (R8):
// A-frag lane l: A[m + (l&15)][kt + (l>>4)*8 + j]; C row=(l>>4)*4+reg, col=l&15.
// aMode 0: plain A. aMode 3 (comb): K=768, part 0 ctx / 1 outs / 2 sh(row=m>>10).
__global__ __launch_bounds__(256, 3) void k_gemm_mfma(
    const float* __restrict__ A, const float* __restrict__ B,
    const float* __restrict__ bias, float* __restrict__ C,
    int M, int N, int K, int act, int aMode,
    const float* __restrict__ A1, const float* __restrict__ A2)
{
    __shared__ __align__(16) _Float16 As[128][40];
    __shared__ __align__(16) _Float16 Bs[128][40];
    int nbn = N >> 7;
    int bx = blockIdx.x % nbn, by = blockIdx.x / nbn;
    int m0 = by << 7, n0 = bx << 7;
    int t = threadIdx.x;
    int w = t >> 6, l = t & 63;
    int wm = w >> 1, wn = w & 1;
    int lc = l & 15, lg = l >> 4;
    f32x4 acc[4][4] = {};
    for (int kt = 0; kt < K; kt += 32) {
        __syncthreads();
        #pragma unroll
        for (int p = 0; p < 4; ++p) {
            int slot = t + p*256;            // 1024 slots: (m, kc)
            int m = slot >> 3, kc = slot & 7;
            int gk = kt + kc*4;
            float4 va;
            if (aMode == 0) {
                va = *(const float4*)(A + (size_t)(m0+m)*K + gk);
            } else {
                int part = gk >> 8, kk = gk & 255;
                const float* P = (part == 0) ? A : ((part == 1) ? A1 : A2);
                int row = (part == 2) ? ((m0+m) >> 10) : (m0+m);
                va = *(const float4*)(P + (size_t)row*256 + kk);
            }
            h2 pa; pa[0] = (_Float16)va.x; pa[1] = (_Float16)va.y;
            h2 pb; pb[0] = (_Float16)va.z; pb[1] = (_Float16)va.w;
            *(float2*)(&As[m][kc*4]) = make_float2(__builtin_bit_cast(float, pa),
                                                   __builtin_bit_cast(float, pb));
            float4 vb = *(const float4*)(B + (size_t)(n0+m)*K + gk);
            h2 qa; qa[0] = (_Float16)vb.x; qa[1] = (_Float16)vb.y;
            h2 qb; qb[0] = (_Float16)vb.z; qb[1] = (_Float16)vb.w;
            *(float2*)(&Bs[m][kc*4]) = make_float2(__builtin_bit_cast(float, qa),
                                                   __builtin_bit_cast(float, qb));
        }
        __syncthreads();
        f16x8 af[4], bf[4];
        #pragma unroll
        for (int mt = 0; mt < 4; ++mt)
            af[mt] = *(const f16x8*)(&As[wm*64 + mt*16 + lc][lg*8]);
        #pragma unroll
        for (int nt = 0; nt < 4; ++nt)
            bf[nt] = *(const f16x8*)(&Bs[wn*64 + nt*16 + lc][lg*8]);
        #pragma unroll
        for (int mt = 0; mt < 4; ++mt)
            #pragma unroll
            for (int nt = 0; nt < 4; ++nt)
                acc[mt][nt] = __builtin_amdgcn_mfma_f32_16x16x32_f16(af[mt], bf[nt], acc[mt][nt], 0, 0, 0);
    }
    #pragma unroll
    for (int nt = 0; nt < 4; ++nt) {
        int col = n0 + wn*64 + nt*16 + lc;
        float bv = bias[col];
        #pragma unroll
        for (int mt = 0; mt < 4; ++mt) {
            int rbase = m0 + wm*64 + mt*16 + lg*4;
            #pragma unroll
            for (int r = 0; r < 4; ++r) {
                float v = acc[mt][nt][r] + bv;
                if (act == 1) v = geluf(v);
                else if (act == 2) v = tanhf(v);
                C[(size_t)(rbase + r)*N + col] = v;
            }
        }
    }
}

// ---------------- causal attention (flash-style), WG = (b, 16 rows) ----------------
__global__ __launch_bounds__(256) void k_attn(
    const float* __restrict__ outs, const float* __restrict__ modif, float* __restrict__ ctx)
{
    __shared__ __align__(16) float Qs[16][256];
    __shared__ __align__(16) float KVs[32][256];
    __shared__ __align__(16) float sS[16][32];
    __shared__ float rowScaleL[16];
    __shared__ float rowLL[16];
    int b = blockIdx.y, l0 = blockIdx.x << 4, t = threadIdx.x;
    for (int idx = t; idx < 1024; idx += 256) {
        int r = idx >> 6, k4 = idx & 63;
        *(float4*)&Qs[r][k4*4] = *(const float4*)(outs + ((size_t)b*1024 + l0 + r)*256 + k4*4);
    }
    int sr = t >> 4, sj = t & 15;
    int rp = t >> 5, cg = t & 31;
    float rowM = -1e30f, rowL = 0.f;
    float accA[8] = {}, accB[8] = {};
    int nt = ((l0 + 14) >> 5) + 1;
    for (int tt = 0; tt < nt; ++tt) {
        int m0 = tt << 5;
        __syncthreads();
        for (int idx = t; idx < 2048; idx += 256) {
            int mm = idx >> 6, k4 = idx & 63;
            *(float4*)&KVs[mm][k4*4] = *(const float4*)(modif + ((size_t)b*1024 + m0 + mm)*256 + k4*4);
        }
        __syncthreads();
        {
            int mp = sj << 1;
            const float4* q4 = (const float4*)Qs[sr];
            const float4* x4 = (const float4*)KVs[mp];
            const float4* y4 = (const float4*)KVs[mp+1];
            float s0 = 0.f, s1 = 0.f;
            #pragma unroll 8
            for (int kk = 0; kk < 64; ++kk) {
                int k = (kk + sj) & 63;
                float4 q = q4[k], x = x4[k], y = y4[k];
                s0 += q.x*x.x + q.y*x.y + q.z*x.z + q.w*x.w;
                s1 += q.x*y.x + q.y*y.y + q.z*y.z + q.w*y.w;
            }
            int l = l0 + sr;
            if (m0 + mp     >= l) s0 = -1e30f;
            if (m0 + mp + 1 >= l) s1 = -1e30f;
            sS[sr][mp] = s0; sS[sr][mp+1] = s1;
        }
        __syncthreads();
        {
            float v0 = sS[sr][sj], v1 = sS[sr][sj+16];
            float mx = fmaxf(v0, v1);
            for (int off = 8; off; off >>= 1) mx = fmaxf(mx, __shfl_xor(mx, off));
            float newM = fmaxf(rowM, mx);
            float scale, p0, p1;
            if (newM < -1e29f) { scale = 1.f; p0 = 0.f; p1 = 0.f; }
            else { scale = expf(rowM - newM); p0 = expf(v0 - newM); p1 = expf(v1 - newM); }
            rowM = newM;
            float ts = p0 + p1;
            for (int off = 8; off; off >>= 1) ts += __shfl_xor(ts, off);
            rowL = rowL*scale + ts;
            sS[sr][sj] = p0; sS[sr][sj+16] = p1;
            if (sj == 0) { rowScaleL[sr] = scale; rowLL[sr] = rowL; }
        }
        __syncthreads();
        for (int idx = t; idx < 2048; idx += 256) {
            int mm = idx >> 6, k4 = idx & 63;
            *(float4*)&KVs[mm][k4*4] = *(const float4*)(outs + ((size_t)b*1024 + m0 + mm)*256 + k4*4);
        }
        __syncthreads();
        {
            float sc0 = rowScaleL[2*rp], sc1 = rowScaleL[2*rp+1];
            #pragma unroll
            for (int j = 0; j < 8; ++j) { accA[j] *= sc0; accB[j] *= sc1; }
            int c0 = cg << 3;
            #pragma unroll 4
            for (int mm = 0; mm < 32; ++mm) {
                float p0 = sS[2*rp][mm], p1 = sS[2*rp+1][mm];
                float4 vA = *(const float4*)&KVs[mm][c0];
                float4 vB = *(const float4*)&KVs[mm][c0+4];
                accA[0] += p0*vA.x; accA[1] += p0*vA.y; accA[2] += p0*vA.z; accA[3] += p0*vA.w;
                accA[4] += p0*vB.x; accA[5] += p0*vB.y; accA[6] += p0*vB.z; accA[7] += p0*vB.w;
                accB[0] += p1*vA.x; accB[1] += p1*vA.y; accB[2] += p1*vA.z; accB[3] += p1*vA.w;
                accB[4] += p1*vB.x; accB[5] += p1*vB.y; accB[6] += p1*vB.z; accB[7] += p1*vB.w;
            }
        }
    }
    __syncthreads();
    int c0 = cg << 3;
    {
        int l = l0 + 2*rp;
        float inv = (l == 0) ? 0.f : 1.f/rowLL[2*rp];
        float4* cp = (float4*)(ctx + ((size_t)b*1024 + l)*256 + c0);
        cp[0] = make_float4(accA[0]*inv, accA[1]*inv, accA[2]*inv, accA[3]*inv);
        cp[1] = make_float4(accA[4]*inv, accA[5]*inv, accA[6]*inv, accA[7]*inv);
    }
    {
        int l = l0 + 2*rp + 1;
        float inv = 1.f/rowLL[2*rp+1];
        float4* cp = (float4*)(ctx + ((size_t)b*1024 + l)*256 + c0);
        cp[0] = make_float4(accB[0]*inv, accB[1]*inv, accB[2]*inv, accB[3]*inv);
        cp[1] = make_float4(accB[4]*inv, accB[5]*inv, accB[6]*inv, accB[7]*inv);
    }
}

// ---------------- final: logits + outputs ----------------
__global__ __launch_bounds__(256) void k_final(
    const float* __restrict__ h2v, const float* __restrict__ w2, const float* __restrict__ b2,
    const float* __restrict__ mask, float* __restrict__ out)
{
    int i = blockIdx.x*256 + threadIdx.x;   // < 32768
    const float4* h4 = (const float4*)(h2v + (size_t)i*256);
    const float4* w4 = (const float4*)w2;
    float a0=0,a1=0,a2=0,a3=0;
    #pragma unroll 8
    for (int k = 0; k < 64; ++k) {
        float4 h = h4[k], w = w4[k];
        a0 += h.x*w.x; a1 += h.y*w.y; a2 += h.z*w.z; a3 += h.w*w.w;
    }
    float lg = a0+a1+a2+a3 + b2[0];
    float p = sigm(lg);
    out[2*i]     = 1.0f - p;
    out[2*i + 1] = p;
    out[65536  + i] = (lg > 0.f) ? 1.0f : ((lg < 0.f) ? -1.0f : 0.0f);
    out[98304  + i] = mask[i];
    out[131072 + i] = lg;
}

extern "C" void kernel_launch(void* const* d_in, const int* in_sizes, int n_in,
                              void* d_out, int out_size, void* d_ws, size_t ws_size,
                              hipStream_t stream)
{
    const float* ne      = (const float*)d_in[0];
    const float* mask    = (const float*)d_in[1];
    const int*   trg     = (const int*)  d_in[2];
    const float* se_w0   = (const float*)d_in[3];
    const float* se_b0   = (const float*)d_in[4];
    const float* se_w1   = (const float*)d_in[5];
    const float* se_b1   = (const float*)d_in[6];
    const float* se_w2   = (const float*)d_in[7];
    const float* se_b2   = (const float*)d_in[8];
    const float* w_ih0   = (const float*)d_in[9];
    const float* w_hh0   = (const float*)d_in[10];
    const float* b_ih0   = (const float*)d_in[11];
    const float* b_hh0   = (const float*)d_in[12];
    const float* w_ih1   = (const float*)d_in[13];
    const float* w_hh1   = (const float*)d_in[14];
    const float* b_ih1   = (const float*)d_in[15];
    const float* b_hh1   = (const float*)d_in[16];
    const float* attn_w1 = (const float*)d_in[17];
    const float* attn_b1 = (const float*)d_in[18];
    const float* comb_w  = (const float*)d_in[19];
    const float* comb_b  = (const float*)d_in[20];
    const float* dec_w0  = (const float*)d_in[21];
    const float* dec_b0  = (const float*)d_in[22];
    const float* dec_w1  = (const float*)d_in[23];
    const float* dec_b1  = (const float*)d_in[24];
    const float* dec_w2  = (const float*)d_in[25];
    const float* dec_b2  = (const float*)d_in[26];

    float* W    = (float*)d_ws;
    float* sh   = W;                    // 8192
    float* o0   = W + 8192;             // [L,B,D] 8388608
    float* xp1  = W + 8396800;          // [L,B,G] 25165824
    float* outs = W + 33562624;         // [B,L,D] 8388608  (total 41951232 floats = 160 MB)
    float* modif = o0;                  // reuse (o0 dead after xp1 GEMM)
    float* ctx  = xp1;                  // reuse (xp1 dead after scan1)
    float* dec  = xp1 + 8388608;
    float* h1   = xp1 + 16777216;
    float* h2b  = o0;                   // reuse (modif dead after attention)
    float* out  = (float*)d_out;

    k_start_embed<<<32, 256, 0, stream>>>(ne, se_w0, se_b0, se_w1, se_b1, se_w2, se_b2, sh);
    k_gru3<0><<<32, 512, 0, stream>>>(w_hh0, b_hh0, w_ih0, b_ih0, nullptr, trg, sh, o0);
    k_gemm_mfma<<<1536, 256, 0, stream>>>(o0, w_ih1, b_ih1, xp1, NROWS, 768, 256, 0, 0, nullptr, nullptr);
    k_gru3<1><<<32, 512, 0, stream>>>(w_hh1, b_hh1, nullptr, nullptr, xp1, trg, sh, outs);
    k_gemm_mfma<<<512, 256, 0, stream>>>(outs, attn_w1, attn_b1, modif, NROWS, 256, 256, 0, 0, nullptr, nullptr);
    { dim3 ag(64, 32); k_attn<<<ag, 256, 0, stream>>>(outs, modif, ctx); }
    k_gemm_mfma<<<512, 256, 0, stream>>>(ctx, comb_w, comb_b, dec, NROWS, 256, 768, 2, 3, outs, sh);
    k_gemm_mfma<<<512, 256, 0, stream>>>(dec, dec_w0, dec_b0, h1, NROWS, 256, 256, 1, 0, nullptr, nullptr);
    k_gemm_mfma<<<512, 256, 0, stream>>>(h1, dec_w1, dec_b1, h2b, NROWS, 256, 256, 1, 0, nullptr, nullptr);
    k_final<<<128, 256, 0, stream>>>(h2b, dec_w2, dec_b2, mask, out);
}